// Round 4
// baseline (617.787 us; speedup 1.0000x reference)
//
#include <hip/hip_runtime.h>
#include <cstddef>

#define NPIX 1024   // H*W = 32*32

// ---------------------------------------------------------------------------
// Workspace layout (float-slot offsets). Peak usage 34,045,952 floats (136 MB)
// -- under the 151 MB proven safe in earlier rounds.
// Persistent: blocked-bf16 weights [0 .. 425984)
// Phase A (per block-iter): xt, qkv(bf16), dpw(bf16), att_t, kvp, t1, t1t
// Phase B: h1 (aliases xt/qkv/dpw/att_t-head), h2t (aliases t1t..), t1 still live
// ---------------------------------------------------------------------------
static constexpr size_t WQKV_OFF = 0;          //  98304 floats (768x256 bf16)
static constexpr size_t WPROJ_OFF = 98304;     //  65536 (256x512)
static constexpr size_t WINV_OFF  = 163840;    // 131072 (1024x256)
static constexpr size_t WPW_OFF   = 294912;    // 131072 (256x1024)
static constexpr size_t XT_OFF    = 425984;    // 2097152 (16x256x1024 bf16 blocked)
static constexpr size_t QKV_OFF   = 2523136;   // 6291456 (16x768x1024 bf16 [c][n])
static constexpr size_t DPW_OFF   = 8814592;   // 6291456
static constexpr size_t ATT_OFF   = 15106048;  // 4194304 (16x512x1024 bf16 blocked)
static constexpr size_t KVP_OFF   = 19300352;  // 2162688 (2048x1056 fp32)
static constexpr size_t T1_OFF    = 21463040;  // 4194304 (16x256x1024 fp32 [c][n])
static constexpr size_t T1T_OFF   = 25657344;  // 2097152 (blocked bf16)
static constexpr size_t H1_OFF    = 425984;    // 16777216 (16x1024x1024 fp32 [c][n])
static constexpr size_t H2T_OFF   = 25657344;  // 8388608 (16x1024x1024 bf16 blocked)

typedef __attribute__((ext_vector_type(8))) short bf16x8;
typedef __attribute__((ext_vector_type(8))) unsigned short u16x8;
typedef __attribute__((ext_vector_type(4))) float f32x4;

__device__ inline unsigned short f2bf(float f) {
    union { float f; unsigned int u; } v; v.f = f;
    unsigned int u = v.u;
    u += 0x7FFFu + ((u >> 16) & 1u);        // round-to-nearest-even
    return (unsigned short)(u >> 16);
}
__device__ inline float bf2f(unsigned short u) {
    union { float f; unsigned int u; } v; v.u = ((unsigned int)u) << 16;
    return v.f;
}

#define GLOAD_LDS16(gp, lp) __builtin_amdgcn_global_load_lds(                  \
    (const __attribute__((address_space(1))) unsigned int*)(const void*)(gp), \
    (__attribute__((address_space(3))) unsigned int*)(void*)(lp), 16, 0, 0)

// ---------------------------------------------------------------------------
// Weight convert: fp32 [O][K] -> blocked bf16 [K/8][O][8]
// ---------------------------------------------------------------------------
__global__ __launch_bounds__(256)
void wconv(const float* __restrict__ W, unsigned short* __restrict__ WB,
           const int O, const int K)
{
    const int idx = blockIdx.x * 256 + threadIdx.x;
    if (idx >= O * (K >> 3)) return;
    const int o = idx % O;
    const int koct = idx / O;
    u16x8 v;
#pragma unroll
    for (int j = 0; j < 8; j++) v[j] = f2bf(W[(size_t)o * K + koct * 8 + j]);
    *(u16x8*)(WB + ((size_t)koct * O + o) * 8) = v;
}

// ---------------------------------------------------------------------------
// Transpose: fp32 [b][C][1024] -> blocked bf16 [b][C/8][1024][8]
// grid: B * (C/8) * 4 strips of 256 px
// ---------------------------------------------------------------------------
__global__ __launch_bounds__(256)
void xpose_f32_bf16(const float* __restrict__ X, unsigned short* __restrict__ XT,
                    const int C)
{
    __shared__ float tt[8][260];
    const int t = threadIdx.x;
    const int octs = C >> 3;
    const int strips = octs * 4;
    const int b = blockIdx.x / strips;
    const int rem = blockIdx.x - b * strips;
    const int coct = rem >> 2;
    const int n0 = (rem & 3) * 256;

    const int cc = t >> 5;
    const int c8 = (t & 31) * 8;
    const float* xp = X + ((size_t)b * C + coct * 8 + cc) * NPIX + n0 + c8;
    *(float4*)(&tt[cc][c8])     = *(const float4*)(xp);
    *(float4*)(&tt[cc][c8 + 4]) = *(const float4*)(xp + 4);
    __syncthreads();
    u16x8 v;
#pragma unroll
    for (int j = 0; j < 8; j++) v[j] = f2bf(tt[j][t]);
    *(u16x8*)(XT + (((size_t)b * octs + coct) * NPIX + n0 + t) * 8) = v;
}

// ---------------------------------------------------------------------------
// MFMA GEMM, blocked-bf16 operands:
//   X: [b][K/8][1024][8] bf16, W: [K/8][O][8] bf16
//   Y[b,o,n] = sum_k W[o,k] X[b,k,n]  (+ epilogue)
// Block tile BM x 128n, 4 waves (2x2): wave (BM/2) x 64.
// Staging: global_load_lds 16B/lane, double-buffered LDS, 1 barrier/K-tile(64).
// LDS rows = 128B (64 bf16 = one K-tile), m201 swizzle: slot ^= 2*((row>>2)&1),
// applied on the GLOBAL source address (LDS dest stays lane-linear).
// EPI: 0 plain, 1 BN+residual(+ACC), 2 bias+hswish.  OBF16: bf16 [c][n] out.
// ---------------------------------------------------------------------------
template<int BM, int EPI, bool ACC, bool OBF16>
__global__ __launch_bounds__(256)
void gemm_blk(const unsigned short* __restrict__ X, const unsigned short* __restrict__ W,
              void* __restrict__ Yv, const int O, const int K,
              const float* __restrict__ res,
              const float* __restrict__ bng, const float* __restrict__ bnb,
              const float* __restrict__ bnm, const float* __restrict__ bnv,
              const float* __restrict__ bias)
{
    constexpr int MI = BM / 32;
    __shared__ unsigned short As[2][BM][64];
    __shared__ unsigned short Bs[2][128][64];

    const int t    = threadIdx.x;
    const int lane = t & 63;
    const int w    = t >> 6;

    // XCD-bijective block swizzle (all grids are multiples of 8)
    const int gx  = gridDim.x;
    const int nwg = gx * gridDim.y;
    int bid = blockIdx.y * gx + blockIdx.x;
    bid = (bid & 7) * (nwg >> 3) + (bid >> 3);
    const int bx = bid % gx;
    const int by = bid / gx;

    const int o0 = bx * BM;
    const int b  = by >> 3;
    const int n0 = (by & 7) * 128;

    const int wo = (w >> 1) * (BM / 2);
    const int wn = (w & 1) * 64;

    f32x4 acc[MI][4];
#pragma unroll
    for (int i = 0; i < MI; i++)
#pragma unroll
        for (int j = 0; j < 4; j++) {
            f32x4 z = {0.f, 0.f, 0.f, 0.f};
            acc[i][j] = z;
        }

    const unsigned short* Xb = X + (size_t)b * K * NPIX;
    const int lr = lane >> 3;      // row-within-8 of this lane's 16B
    const int sp = lane & 7;       // physical 16B slot

    // stage one K-tile (64 k) into buffer d via global_load_lds.
    // LDS dest is lane-linear; swizzle folded into the global source slot.
    auto stage = [&](int d, int k0) {
        const int kb = k0 >> 3;
        // B: 128 rows, 4 issues/wave of 8 rows
#pragma unroll
        for (int i = 0; i < 4; i++) {
            const int r0 = w * 32 + i * 8;
            const int r  = r0 + lr;
            const int sl = sp ^ (2 * ((r >> 2) & 1));
            const unsigned short* gp = Xb + (((size_t)(kb + sl)) * NPIX + n0 + r) * 8;
            GLOAD_LDS16(gp, &Bs[d][r0][0]);
        }
        // A: BM rows, BM/32 issues/wave
#pragma unroll
        for (int i = 0; i < BM / 32; i++) {
            const int r0 = w * (BM / 4) + i * 8;
            const int r  = r0 + lr;
            const int sl = sp ^ (2 * ((r >> 2) & 1));
            const unsigned short* gp = W + (((size_t)(kb + sl)) * O + o0 + r) * 8;
            GLOAD_LDS16(gp, &As[d][r0][0]);
        }
    };

    stage(0, 0);
    __syncthreads();                   // compiler drains vmcnt(0) at barrier

    const int l16 = lane & 15;
    const int lq  = lane >> 4;

    int cur = 0;
    for (int k0 = 0; k0 < K; k0 += 64) {
        if (k0 + 64 < K) stage(cur ^ 1, k0 + 64);
#pragma unroll
        for (int kk = 0; kk < 2; kk++) {
            bf16x8 afr[MI], bfr[4];
#pragma unroll
            for (int i = 0; i < MI; i++) {
                const int r = wo + i * 16 + l16;
                afr[i] = *(const bf16x8*)&As[cur][r][((kk * 4 + lq) ^ (2 * ((r >> 2) & 1))) * 8];
            }
#pragma unroll
            for (int j = 0; j < 4; j++) {
                const int r = wn + j * 16 + l16;
                bfr[j] = *(const bf16x8*)&Bs[cur][r][((kk * 4 + lq) ^ (2 * ((r >> 2) & 1))) * 8];
            }
#pragma unroll
            for (int i = 0; i < MI; i++)
#pragma unroll
                for (int j = 0; j < 4; j++)
                    acc[i][j] = __builtin_amdgcn_mfma_f32_16x16x32_bf16(
                        afr[i], bfr[j], acc[i][j], 0, 0, 0);
        }
        __syncthreads();
        cur ^= 1;
    }

    // epilogue. C/D: col = lane&15 (n), row = (lane>>4)*4 + reg (o)
    float* Y = (float*)Yv;
    unsigned short* Yb = (unsigned short*)Yv;
    const int r0q = lq * 4;
    float scale[MI][4], shift[MI][4];
    if (EPI == 1) {
#pragma unroll
        for (int i = 0; i < MI; i++)
#pragma unroll
            for (int r = 0; r < 4; r++) {
                const int o = o0 + wo + i * 16 + r0q + r;
                const float inv = bng[o] / sqrtf(bnv[o] + 1e-5f);
                scale[i][r] = inv;
                shift[i][r] = bnb[o] - bnm[o] * inv;
            }
    } else if (EPI == 2) {
#pragma unroll
        for (int i = 0; i < MI; i++)
#pragma unroll
            for (int r = 0; r < 4; r++)
                shift[i][r] = bias[o0 + wo + i * 16 + r0q + r];
    }
#pragma unroll
    for (int i = 0; i < MI; i++) {
#pragma unroll
        for (int j = 0; j < 4; j++) {
            const int nn = n0 + wn + j * 16 + l16;
            const size_t base = ((size_t)b * O + o0 + wo + i * 16 + r0q) * NPIX + nn;
#pragma unroll
            for (int r = 0; r < 4; r++) {
                const size_t off = base + (size_t)r * NPIX;
                float v = acc[i][j][r];
                if (EPI == 1) {
                    v = v * scale[i][r] + shift[i][r] + res[off];
                } else if (EPI == 2) {
                    v += shift[i][r];
                    v = v * fminf(fmaxf(v + 3.f, 0.f), 6.f) * (1.f / 6.f);
                }
                if (OBF16) {
                    Yb[off] = f2bf(v);
                } else {
                    if (ACC) v += Y[off];
                    Y[off] = v;
                }
            }
        }
    }
}

// ---------------------------------------------------------------------------
// Depthwise 5x5 SAME, bf16 in/out, one (b,c) 32x32 plane per block.
// ---------------------------------------------------------------------------
__global__ __launch_bounds__(256)
void dwconv5x5(const unsigned short* __restrict__ X, const float* __restrict__ Wd,
               unsigned short* __restrict__ Y)
{
    __shared__ float tile[36 * 36];
    __shared__ float wl[25];
    const int t  = threadIdx.x;
    const int bc = blockIdx.x;            // b*768 + c
    const int c  = bc % 768;
    const unsigned short* xp = X + (size_t)bc * NPIX;
    if (t < 25) wl[t] = Wd[c * 25 + t];
    for (int i = t; i < 36 * 36; i += 256) {
        const int r = i / 36 - 2;
        const int q = i % 36 - 2;
        tile[i] = (r >= 0 && r < 32 && q >= 0 && q < 32) ? bf2f(xp[r * 32 + q]) : 0.f;
    }
    __syncthreads();
#pragma unroll
    for (int p = 0; p < 4; p++) {
        const int px = t + p * 256;
        const int h = px >> 5, w = px & 31;
        float s = 0.f;
#pragma unroll
        for (int ky = 0; ky < 5; ky++)
#pragma unroll
            for (int kx = 0; kx < 5; kx++)
                s = fmaf(tile[(h + ky) * 36 + (w + kx)], wl[ky * 5 + kx], s);
        Y[(size_t)bc * NPIX + px] = f2bf(s);
    }
}

// ---------------------------------------------------------------------------
// Grouped 32->32 1x1 (24 groups), in-place on bf16 D.
// ---------------------------------------------------------------------------
__global__ __launch_bounds__(256)
void grouped_pw(unsigned short* __restrict__ D, const float* __restrict__ Wg)
{
    __shared__ float ws[1024];
    const int t     = threadIdx.x;
    const int blk   = blockIdx.x;          // (b*24+g)*4 + chunk
    const int chunk = blk & 3;
    const int bg    = blk >> 2;
    const int g     = bg % 24;
    const int b     = bg / 24;
    for (int i = t; i < 1024; i += 256) ws[i] = Wg[g * 1024 + i];
    __syncthreads();
    const int px = chunk * 256 + t;
    unsigned short* dp = D + ((size_t)(b * 768 + g * 32)) * NPIX + px;
    float in[32];
#pragma unroll
    for (int i = 0; i < 32; i++) in[i] = bf2f(dp[(size_t)i * NPIX]);
#pragma unroll
    for (int o = 0; o < 32; o++) {
        float s = 0.f;
#pragma unroll
        for (int i = 0; i < 32; i++) s = fmaf(ws[o * 32 + i], in[i], s);
        dp[(size_t)o * NPIX] = f2bf(s);
    }
}

// ---------------------------------------------------------------------------
// Attention phase 1: partial kv[33][32] per (b,h,chunk-of-128-pixels), bf16 in.
// ---------------------------------------------------------------------------
__global__ __launch_bounds__(256)
void attn_kv_partial(const unsigned short* __restrict__ qkv,
                     const unsigned short* __restrict__ dpw,
                     float* __restrict__ kvp)
{
    __shared__ float Ks[32][130];
    __shared__ float Vs[32][130];
    const int t   = threadIdx.x;
    const int blk = blockIdx.x;           // bh*8 + ch
    const int ch  = blk & 7;
    const int bh  = blk >> 3;
    const int b   = bh >> 4;
    const int h   = bh & 15;
    const unsigned short* base = (h < 8)
        ? qkv + ((size_t)(b * 768 + h * 96)) * NPIX
        : dpw + ((size_t)(b * 768 + (h - 8) * 96)) * NPIX;
    const unsigned short* kp = base + 32 * NPIX + ch * 128;
    const unsigned short* vp = base + 64 * NPIX + ch * 128;
    const int srow = t >> 3;              // 0..31
    const int scol = (t & 7) * 16;        // 0..112
    {
        const u16x8 ka = *(const u16x8*)(kp + (size_t)srow * NPIX + scol);
        const u16x8 kb = *(const u16x8*)(kp + (size_t)srow * NPIX + scol + 8);
        const u16x8 va = *(const u16x8*)(vp + (size_t)srow * NPIX + scol);
        const u16x8 vb = *(const u16x8*)(vp + (size_t)srow * NPIX + scol + 8);
#pragma unroll
        for (int j = 0; j < 8; j++) {
            Ks[srow][scol + j]     = fmaxf(bf2f(ka[j]), 0.f);
            Ks[srow][scol + 8 + j] = fmaxf(bf2f(kb[j]), 0.f);
            Vs[srow][scol + j]     = bf2f(va[j]);
            Vs[srow][scol + 8 + j] = bf2f(vb[j]);
        }
    }
    __syncthreads();
    float* outp = kvp + (size_t)blk * 1056;
#pragma unroll
    for (int i = 0; i < 4; i++) {
        const int p = t + i * 256;
        const int d = p >> 5;
        const int e = p & 31;
        float a = 0.f;
        for (int nn = 0; nn < 128; nn += 2) {
            const float2 kk = *(const float2*)(&Ks[e][nn]);
            const float2 vv = *(const float2*)(&Vs[d][nn]);
            a = fmaf(vv.x, kk.x, a);
            a = fmaf(vv.y, kk.y, a);
        }
        outp[p] = a;
    }
    if (t < 32) {
        float a = 0.f;
        for (int nn = 0; nn < 128; nn += 2) {
            const float2 kk = *(const float2*)(&Ks[t][nn]);
            a += kk.x + kk.y;
        }
        outp[1024 + t] = a;
    }
}

// ---------------------------------------------------------------------------
// Attention phase 2: reduce kv partials, apply; OUT = blocked bf16
// att_t[b][64][1024][8]  (c = h*32 + db*8 + j)
// ---------------------------------------------------------------------------
__global__ __launch_bounds__(256)
void attn_apply(const unsigned short* __restrict__ qkv,
                const unsigned short* __restrict__ dpw,
                const float* __restrict__ kvp, unsigned short* __restrict__ att)
{
    __shared__ float kvs[1056];
    const int t   = threadIdx.x;
    const int blk = blockIdx.x;           // bh*4 + qc
    const int qc  = blk & 3;
    const int bh  = blk >> 2;
    const int b   = bh >> 4;
    const int h   = bh & 15;
    for (int idx = t; idx < 1056; idx += 256) {
        float s = 0.f;
#pragma unroll
        for (int ch = 0; ch < 8; ch++)
            s += kvp[((size_t)bh * 8 + ch) * 1056 + idx];
        kvs[idx] = s;
    }
    __syncthreads();
    const unsigned short* qp = (h < 8)
        ? qkv + ((size_t)(b * 768 + h * 96)) * NPIX
        : dpw + ((size_t)(b * 768 + (h - 8) * 96)) * NPIX;
    const int n = qc * 256 + t;
    float q[32];
#pragma unroll
    for (int e = 0; e < 32; e++) q[e] = fmaxf(bf2f(qp[(size_t)e * NPIX + n]), 0.f);
    float den = 0.f;
#pragma unroll
    for (int e = 0; e < 32; e++) den = fmaf(kvs[1024 + e], q[e], den);
    const float inv = 1.f / (den + 1e-15f);
#pragma unroll
    for (int db = 0; db < 4; db++) {
        u16x8 o8;
#pragma unroll
        for (int jj = 0; jj < 8; jj++) {
            const int d = db * 8 + jj;
            float a = 0.f;
#pragma unroll
            for (int e = 0; e < 32; e++) a = fmaf(kvs[d * 32 + e], q[e], a);
            o8[jj] = f2bf(a * inv);
        }
        *(u16x8*)(att + (((size_t)(b * 64 + h * 4 + db)) * NPIX + n) * 8) = o8;
    }
}

// ---------------------------------------------------------------------------
// Depthwise 3x3 + bias + hswish, fp32 [c][n] in -> blocked bf16 out
// h2t[b][128 oct][1024 n][8].  One (b, 8-channel oct) per block.
// ---------------------------------------------------------------------------
__global__ __launch_bounds__(256)
void dwconv3x3t(const float* __restrict__ X, const float* __restrict__ Wd,
                const float* __restrict__ bias, unsigned short* __restrict__ Y)
{
    __shared__ float tile[8][1156];   // 34*34 per channel
    __shared__ float wl[8][9];
    __shared__ float bb[8];
    const int t   = threadIdx.x;
    const int oct = blockIdx.x & 127;
    const int b   = blockIdx.x >> 7;
    const float* xp = X + ((size_t)b * 1024 + oct * 8) * NPIX;
    if (t < 72) wl[t / 9][t % 9] = Wd[(oct * 8 + t / 9) * 9 + t % 9];
    if (t < 8) bb[t] = bias[oct * 8 + t];
    for (int i = t; i < 8 * 1156; i += 256) {
        const int cc = i / 1156;
        const int p  = i - cc * 1156;
        const int r  = p / 34 - 1;
        const int q  = p % 34 - 1;
        tile[cc][p] = (r >= 0 && r < 32 && q >= 0 && q < 32)
                      ? xp[(size_t)cc * NPIX + r * 32 + q] : 0.f;
    }
    __syncthreads();
#pragma unroll
    for (int p = 0; p < 4; p++) {
        const int px = t + p * 256;
        const int hh = px >> 5, ww = px & 31;
        u16x8 o8;
#pragma unroll
        for (int cc = 0; cc < 8; cc++) {
            float s = bb[cc];
#pragma unroll
            for (int ky = 0; ky < 3; ky++)
#pragma unroll
                for (int kx = 0; kx < 3; kx++)
                    s = fmaf(tile[cc][(hh + ky) * 34 + (ww + kx)], wl[cc][ky * 3 + kx], s);
            s = s * fminf(fmaxf(s + 3.f, 0.f), 6.f) * (1.f / 6.f);
            o8[cc] = f2bf(s);
        }
        *(u16x8*)(Y + (((size_t)(b * 128 + oct)) * NPIX + px) * 8) = o8;
    }
}

// ---------------------------------------------------------------------------
extern "C" void kernel_launch(void* const* d_in, const int* in_sizes, int n_in,
                              void* d_out, int out_size, void* d_ws, size_t ws_size,
                              hipStream_t stream)
{
    (void)in_sizes; (void)n_in; (void)out_size; (void)ws_size;

    const float* x      = (const float*)d_in[0];
    const float* y      = (const float*)d_in[1];
    const float* qkv_w  = (const float*)d_in[2];
    const float* dw5_w  = (const float*)d_in[3];
    const float* pwg_w  = (const float*)d_in[4];
    const float* proj_w = (const float*)d_in[5];
    const float* proj_g = (const float*)d_in[6];
    const float* proj_b = (const float*)d_in[7];
    const float* proj_m = (const float*)d_in[8];
    const float* proj_v = (const float*)d_in[9];
    const float* inv_w  = (const float*)d_in[10];
    const float* inv_b  = (const float*)d_in[11];
    const float* dwc_w  = (const float*)d_in[12];
    const float* dwc_b  = (const float*)d_in[13];
    const float* pw_w   = (const float*)d_in[14];
    const float* pw_g   = (const float*)d_in[15];
    const float* pw_b   = (const float*)d_in[16];
    const float* pw_m   = (const float*)d_in[17];
    const float* pw_v   = (const float*)d_in[18];

    float* ws = (float*)d_ws;
    unsigned short* wqkv_b = (unsigned short*)(ws + WQKV_OFF);
    unsigned short* wproj_b= (unsigned short*)(ws + WPROJ_OFF);
    unsigned short* winv_b = (unsigned short*)(ws + WINV_OFF);
    unsigned short* wpw_b  = (unsigned short*)(ws + WPW_OFF);
    unsigned short* wxt    = (unsigned short*)(ws + XT_OFF);
    unsigned short* wqkv   = (unsigned short*)(ws + QKV_OFF);
    unsigned short* wdpw   = (unsigned short*)(ws + DPW_OFF);
    unsigned short* watt   = (unsigned short*)(ws + ATT_OFF);
    float*          wkvp   = ws + KVP_OFF;
    float*          wt1    = ws + T1_OFF;
    unsigned short* wt1t   = (unsigned short*)(ws + T1T_OFF);
    float*          wh1    = ws + H1_OFF;
    unsigned short* wh2t   = (unsigned short*)(ws + H2T_OFF);
    float* out = (float*)d_out;

    // weights -> blocked bf16 (once per launch)
    wconv<<<dim3(96),  256, 0, stream>>>(qkv_w,  wqkv_b,  768, 256);
    wconv<<<dim3(64),  256, 0, stream>>>(proj_w, wproj_b, 256, 512);
    wconv<<<dim3(128), 256, 0, stream>>>(inv_w,  winv_b,  1024, 256);
    wconv<<<dim3(128), 256, 0, stream>>>(pw_w,   wpw_b,   256, 1024);

    for (int blk = 0; blk < 2; blk++) {
        const float* t = (blk == 0) ? x : y;

        // --- lite_mla ---
        xpose_f32_bf16<<<dim3(2048), 256, 0, stream>>>(t, wxt, 256);
        gemm_blk<128, 0, false, true><<<dim3(6, 128), 256, 0, stream>>>(
            wxt, wqkv_b, wqkv, 768, 256,
            nullptr, nullptr, nullptr, nullptr, nullptr, nullptr);
        dwconv5x5<<<dim3(12288), 256, 0, stream>>>(wqkv, dw5_w, wdpw);
        grouped_pw<<<dim3(1536), 256, 0, stream>>>(wdpw, pwg_w);
        attn_kv_partial<<<dim3(2048), 256, 0, stream>>>(wqkv, wdpw, wkvp);
        attn_apply<<<dim3(1024), 256, 0, stream>>>(wqkv, wdpw, wkvp, watt);
        gemm_blk<64, 1, false, false><<<dim3(4, 128), 256, 0, stream>>>(
            watt, wproj_b, wt1, 256, 512,
            t, proj_g, proj_b, proj_m, proj_v, nullptr);

        // --- mbconv ---
        xpose_f32_bf16<<<dim3(2048), 256, 0, stream>>>(wt1, wt1t, 256);
        gemm_blk<128, 2, false, false><<<dim3(8, 128), 256, 0, stream>>>(
            wt1t, winv_b, wh1, 1024, 256,
            nullptr, nullptr, nullptr, nullptr, nullptr, inv_b);
        dwconv3x3t<<<dim3(2048), 256, 0, stream>>>(wh1, dwc_w, dwc_b, wh2t);
        if (blk == 0) {
            gemm_blk<64, 1, false, false><<<dim3(4, 128), 256, 0, stream>>>(
                wh2t, wpw_b, out, 256, 1024,
                wt1, pw_g, pw_b, pw_m, pw_v, nullptr);
        } else {
            gemm_blk<64, 1, true, false><<<dim3(4, 128), 256, 0, stream>>>(
                wh2t, wpw_b, out, 256, 1024,
                wt1, pw_g, pw_b, pw_m, pw_v, nullptr);
        }
    }
}